// Round 1
// baseline (6409.499 us; speedup 1.0000x reference)
//
#include <hip/hip_runtime.h>

#define P 16384
#define NLAYERS 5
#define NND 98304          // P*(NLAYERS+1)
#define D 64
#define S 16
#define F 80               // D+S
#define H 256
#define EDG 262144
#define NG 64

// ---------------------------------------------------------------- utilities
__device__ __forceinline__ void fatomic_add(float* p, float v) {
    unsafeAtomicAdd(p, v);   // global_atomic_add_f32 on gfx950
}

// ---------------------------------------------------------------- init X
__global__ void k_init_x(const float* __restrict__ x0, float* __restrict__ X) {
    int idx = blockIdx.x * blockDim.x + threadIdx.x;
    if (idx >= NND * D) return;
    int row = idx >> 6, f = idx & 63;
    X[idx] = (f == 0) ? x0[row] : 0.0f;
}

// ---------------------------------------------------------------- T = scale * concat(X, static)
// T rows are local [0,P) mapping to global rows gbase+v
__global__ void k_build_T(const float* __restrict__ X, const float* __restrict__ st,
                          float* __restrict__ T, int gbase,
                          const float* __restrict__ eps, int ei) {
    int idx = blockIdx.x * blockDim.x + threadIdx.x;
    if (idx >= P * F) return;
    int v = idx / F, f = idx - v * F;
    float scale = (ei >= 0) ? (1.0f + eps[ei]) : 1.0f;
    int g = gbase + v;
    float val = (f < D) ? X[(size_t)g * D + f] : st[(size_t)g * S + (f - D)];
    T[idx] = scale * val;
}

// ---------------------------------------------------------------- edge aggregation (atomics)
// T[dst[e]][f] += concat(X,static)[src_gbase + src[e]][f]
__global__ void k_edge_aggr(const float* __restrict__ X, const float* __restrict__ st,
                            const int* __restrict__ src, const int* __restrict__ dst,
                            float* __restrict__ T, int src_gbase) {
    int idx = blockIdx.x * blockDim.x + threadIdx.x;
    if (idx >= EDG * 20) return;
    int e = idx / 20, q = idx - e * 20;
    int s = src_gbase + src[e];
    int dl = dst[e];
    int f = q * 4;
    const float* srcp = (f < D) ? &X[(size_t)s * D + f]
                                : &st[(size_t)s * S + (f - D)];
    float4 val = *(const float4*)srcp;
    float* tp = &T[(size_t)dl * F + f];
    fatomic_add(tp + 0, val.x);
    fatomic_add(tp + 1, val.y);
    fatomic_add(tp + 2, val.z);
    fatomic_add(tp + 3, val.w);
}

// ---------------------------------------------------------------- fp32 tiled GEMM + bias + relu
// C[M,N] = relu(A[M,K] @ W[K,N] + b[N]).  M%64==0, N%64==0, K%16==0.
#define BM 64
#define BN 64
#define BK 16
#define TM 4
#define TN 4
__global__ __launch_bounds__(256) void k_gemm(const float* __restrict__ A,
                                              const float* __restrict__ W,
                                              const float* __restrict__ bias,
                                              float* __restrict__ C,
                                              int M, int K, int N) {
    __shared__ float As[BK][BM];
    __shared__ float Bs[BK][BN];
    int tid = threadIdx.x;
    int tx = tid & 15, ty = tid >> 4;
    int row0 = blockIdx.y * BM, col0 = blockIdx.x * BN;

    float acc[TM][TN] = {};

    // A-tile load mapping: m = tid>>2 (64 rows), k4 = (tid&3)*4 -> 64B/row coalesced
    int am = tid >> 2;
    int ak = (tid & 3) * 4;
    // B-tile load mapping: kb = tid>>4 (16 rows of W), n4 = (tid&15)*4 -> 256B coalesced
    int kb = tid >> 4;
    int n4 = (tid & 15) * 4;

    for (int k0 = 0; k0 < K; k0 += BK) {
        float4 av = *(const float4*)&A[(size_t)(row0 + am) * K + k0 + ak];
        As[ak + 0][am] = av.x;
        As[ak + 1][am] = av.y;
        As[ak + 2][am] = av.z;
        As[ak + 3][am] = av.w;
        float4 bv = *(const float4*)&W[(size_t)(k0 + kb) * N + col0 + n4];
        *(float4*)&Bs[kb][n4] = bv;
        __syncthreads();
#pragma unroll
        for (int k = 0; k < BK; ++k) {
            float4 a4 = *(const float4*)&As[k][ty * TM];
            float4 b4 = *(const float4*)&Bs[k][tx * TN];
            float a[TM] = {a4.x, a4.y, a4.z, a4.w};
            float b[TN] = {b4.x, b4.y, b4.z, b4.w};
#pragma unroll
            for (int i = 0; i < TM; ++i)
#pragma unroll
                for (int j = 0; j < TN; ++j) acc[i][j] += a[i] * b[j];
        }
        __syncthreads();
    }

#pragma unroll
    for (int i = 0; i < TM; ++i) {
        int r = row0 + ty * TM + i;
#pragma unroll
        for (int j = 0; j < TN; ++j) {
            int c = col0 + tx * TN + j;
            float v = acc[i][j] + bias[c];
            C[(size_t)r * N + c] = fmaxf(v, 0.0f);
        }
    }
}

// ---------------------------------------------------------------- pooling
__global__ void k_pool(const float* __restrict__ X, const int* __restrict__ bidx,
                       float* __restrict__ pooled) {
    int idx = blockIdx.x * blockDim.x + threadIdx.x;
    if (idx >= NND * D) return;
    int row = idx >> 6, f = idx & 63;
    fatomic_add(&pooled[bidx[row] * D + f], X[idx]);
}

// ---------------------------------------------------------------- final linear head
__global__ void k_final(const float* __restrict__ pooled, const float* __restrict__ lin_w,
                        const float* __restrict__ lin_b, float* __restrict__ out) {
    int g = threadIdx.x;
    if (g >= NG) return;
    float acc = lin_b[0];
#pragma unroll
    for (int d2 = 0; d2 < D; ++d2) acc += pooled[g * D + d2] * lin_w[d2];
    out[g] = fmaxf(acc, 0.0f);
}

// ---------------------------------------------------------------- launch
extern "C" void kernel_launch(void* const* d_in, const int* in_sizes, int n_in,
                              void* d_out, int out_size, void* d_ws, size_t ws_size,
                              hipStream_t stream) {
    const float* x0    = (const float*)d_in[0];
    const float* stat  = (const float*)d_in[1];
    const float* W1    = (const float*)d_in[2];
    const float* b1    = (const float*)d_in[3];
    const float* W2    = (const float*)d_in[4];
    const float* b2    = (const float*)d_in[5];
    const float* W3    = (const float*)d_in[6];
    const float* b3    = (const float*)d_in[7];
    const float* eps   = (const float*)d_in[8];
    const float* lin_w = (const float*)d_in[9];
    const float* lin_b = (const float*)d_in[10];
    const int* inner_src = (const int*)d_in[11];
    const int* inner_dst = (const int*)d_in[12];
    const int* fwd_src   = (const int*)d_in[13];
    const int* fwd_dst   = (const int*)d_in[14];
    const int* bwd_src   = (const int*)d_in[15];
    const int* bwd_dst   = (const int*)d_in[16];
    const int* bidx      = (const int*)d_in[17];

    float* X  = (float*)d_ws;                    // NND*D
    float* T  = X  + (size_t)NND * D;            // P*F
    float* H1 = T  + (size_t)P * F;              // P*H
    float* H2 = H1 + (size_t)P * H;              // P*H
    float* PL = H2 + (size_t)P * H;              // NG*D

    auto gemm = [&](const float* A, const float* Wm, const float* bs, float* C,
                    int M, int K, int N) {
        dim3 grid(N / BN, M / BM);
        k_gemm<<<grid, 256, 0, stream>>>(A, Wm, bs, C, M, K, N);
    };
    auto mlp = [&](int wi, float* xout) {
        gemm(T,  W1 + (size_t)wi * F * H, b1 + wi * H, H1, P, F, H);
        gemm(H1, W2 + (size_t)wi * H * H, b2 + wi * H, H2, P, H, H);
        gemm(H2, W3 + (size_t)wi * H * D, b3 + wi * D, xout, P, H, D);
    };
    auto build = [&](int gbase, int ei) {
        k_build_T<<<(P * F + 255) / 256, 256, 0, stream>>>(X, stat, T, gbase, eps, ei);
    };
    auto edges = [&](const int* src, const int* dst, int src_gbase) {
        k_edge_aggr<<<(EDG * 20 + 255) / 256, 256, 0, stream>>>(X, stat, src, dst, T, src_gbase);
    };

    k_init_x<<<(NND * D + 255) / 256, 256, 0, stream>>>(x0, X);

    // forward pass
    for (int il = 0; il < NLAYERS; ++il) {
        int s0 = il * P;
        // inner conv (mlp 0, eps 0)
        build(s0, 0);
        edges(inner_src + (size_t)il * EDG, inner_dst + (size_t)il * EDG, s0);
        mlp(0, X + (size_t)s0 * D);
        if (il == NLAYERS - 1) continue;
        // forward conv (mlp 1, eps 1): src layer il, dst layer il+1
        build(s0 + P, 1);
        edges(fwd_src + (size_t)il * EDG, fwd_dst + (size_t)il * EDG, s0);
        mlp(1, X + (size_t)(s0 + P) * D);
        // node_dnn (mlp 3) on layer il+1
        build(s0 + P, -1);
        mlp(3, X + (size_t)(s0 + P) * D);
    }
    // backward pass
    for (int il = NLAYERS - 1; il >= 1; --il) {
        int s0 = (il - 1) * P;
        // backward conv (mlp 2, eps 2): src layer il, dst layer il-1
        build(s0, 2);
        edges(bwd_src + (size_t)(il - 1) * EDG, bwd_dst + (size_t)(il - 1) * EDG, s0 + P);
        mlp(2, X + (size_t)s0 * D);
        // inner conv on layer il-1
        build(s0, 0);
        edges(inner_src + (size_t)(il - 1) * EDG, inner_dst + (size_t)(il - 1) * EDG, s0);
        mlp(0, X + (size_t)s0 * D);
        // node_dnn on layer il-1
        build(s0, -1);
        mlp(3, X + (size_t)s0 * D);
    }

    hipMemsetAsync(PL, 0, NG * D * sizeof(float), stream);
    k_pool<<<(NND * D + 255) / 256, 256, 0, stream>>>(X, bidx, PL);
    k_final<<<1, 64, 0, stream>>>(PL, lin_w, lin_b, (float*)d_out);
}

// Round 2
// 2574.662 us; speedup vs baseline: 2.4895x; 2.4895x over previous
//
#include <hip/hip_runtime.h>

#define P 16384
#define NLAYERS 5
#define NND 98304          // P*(NLAYERS+1)
#define D 64
#define S 16
#define F 80               // D+S
#define H 256
#define EDG 262144         // 1<<18
#define NG 64
#define NSETS 13           // 5 inner + 4 fwd + 4 bwd
#define RSP 16385          // rowstart pitch (P+1)

// ---------------------------------------------------------------- utilities
__device__ __forceinline__ void fatomic_add(float* p, float v) {
    unsafeAtomicAdd(p, v);   // global_atomic_add_f32 on gfx950
}

// ---------------------------------------------------------------- init X
__global__ void k_init_x(const float* __restrict__ x0, float* __restrict__ X) {
    int idx = blockIdx.x * blockDim.x + threadIdx.x;
    if (idx >= NND * D) return;
    int row = idx >> 6, f = idx & 63;
    X[idx] = (f == 0) ? x0[row] : 0.0f;
}

// ---------------------------------------------------------------- CSR build (batched over all 13 sets)
__device__ __forceinline__ const int* set_ptr(int t, const int* inner, const int* fwd,
                                              const int* bwd) {
    if (t < 5) return inner + (size_t)t * EDG;
    if (t < 9) return fwd + (size_t)(t - 5) * EDG;
    return bwd + (size_t)(t - 9) * EDG;
}

__global__ void k_csr_hist(const int* __restrict__ inner_dst, const int* __restrict__ fwd_dst,
                           const int* __restrict__ bwd_dst, int* __restrict__ deg) {
    int idx = blockIdx.x * blockDim.x + threadIdx.x;
    if (idx >= NSETS * EDG) return;
    int t = idx >> 18, e = idx & (EDG - 1);
    const int* dstp = set_ptr(t, inner_dst, fwd_dst, bwd_dst);
    atomicAdd(&deg[t * P + dstp[e]], 1);
}

__global__ __launch_bounds__(1024) void k_csr_scan(const int* __restrict__ deg,
                                                   int* __restrict__ rowstart) {
    __shared__ int part[1024];
    int t = blockIdx.x;
    const int* d = deg + t * P;
    int* rs = rowstart + (size_t)t * RSP;
    int tid = threadIdx.x;
    int base = tid * 16;
    int loc[16], sum = 0;
#pragma unroll
    for (int i = 0; i < 16; ++i) { loc[i] = sum; sum += d[base + i]; }
    part[tid] = sum;
    __syncthreads();
    for (int off = 1; off < 1024; off <<= 1) {
        int v = (tid >= off) ? part[tid - off] : 0;
        __syncthreads();
        part[tid] += v;
        __syncthreads();
    }
    int pre = tid ? part[tid - 1] : 0;
#pragma unroll
    for (int i = 0; i < 16; ++i) rs[base + i] = pre + loc[i];
    if (tid == 1023) rs[P] = pre + sum;
}

__global__ void k_csr_scatter(const int* __restrict__ inner_src, const int* __restrict__ inner_dst,
                              const int* __restrict__ fwd_src, const int* __restrict__ fwd_dst,
                              const int* __restrict__ bwd_src, const int* __restrict__ bwd_dst,
                              const int* __restrict__ rowstart, int* __restrict__ cursor,
                              int* __restrict__ elist) {
    int idx = blockIdx.x * blockDim.x + threadIdx.x;
    if (idx >= NSETS * EDG) return;
    int t = idx >> 18, e = idx & (EDG - 1);
    const int* srcp = set_ptr(t, inner_src, fwd_src, bwd_src);
    const int* dstp = set_ptr(t, inner_dst, fwd_dst, bwd_dst);
    int dv = dstp[e];
    int pos = atomicAdd(&cursor[t * P + dv], 1);
    elist[(size_t)t * EDG + rowstart[(size_t)t * RSP + dv] + pos] = srcp[e];
}

// ---------------------------------------------------------------- gather conv input
// T[v][:] = (1+eps[ei]) * concat(X,st)[dst_gbase+v][:] + sum_{s in adj(v)} concat(X,st)[src_gbase+s][:]
__global__ __launch_bounds__(256) void k_gather_T(const float* __restrict__ X,
                                                  const float* __restrict__ st,
                                                  const int* __restrict__ elist,
                                                  const int* __restrict__ rowstart,
                                                  float* __restrict__ T,
                                                  int dst_gbase, int src_gbase,
                                                  const float* __restrict__ eps, int ei) {
    int idx = blockIdx.x * blockDim.x + threadIdx.x;   // P*20 threads exactly
    int v = idx / 20, q = idx - v * 20;
    int f = q * 4;
    int beg = rowstart[v], end = rowstart[v + 1];
    float scale = 1.0f + eps[ei];
    int g = dst_gbase + v;
    float4 acc;
    if (f < D) acc = *(const float4*)&X[(size_t)g * D + f];
    else       acc = *(const float4*)&st[(size_t)g * S + (f - D)];
    acc.x *= scale; acc.y *= scale; acc.z *= scale; acc.w *= scale;
    for (int i = beg; i < end; ++i) {
        int s = src_gbase + elist[i];
        float4 val;
        if (f < D) val = *(const float4*)&X[(size_t)s * D + f];
        else       val = *(const float4*)&st[(size_t)s * S + (f - D)];
        acc.x += val.x; acc.y += val.y; acc.z += val.z; acc.w += val.w;
    }
    *(float4*)&T[(size_t)v * F + f] = acc;
}

// ---------------------------------------------------------------- T for node_dnn (no aggregation)
__global__ void k_build_T(const float* __restrict__ X, const float* __restrict__ st,
                          float* __restrict__ T, int gbase) {
    int idx = blockIdx.x * blockDim.x + threadIdx.x;
    if (idx >= P * F) return;
    int v = idx / F, f = idx - v * F;
    int g = gbase + v;
    T[idx] = (f < D) ? X[(size_t)g * D + f] : st[(size_t)g * S + (f - D)];
}

// ---------------------------------------------------------------- fp32 tiled GEMM + bias + relu
#define BM 64
#define BN 64
#define BK 16
#define TM 4
#define TN 4
__global__ __launch_bounds__(256) void k_gemm(const float* __restrict__ A,
                                              const float* __restrict__ W,
                                              const float* __restrict__ bias,
                                              float* __restrict__ C,
                                              int M, int K, int N) {
    __shared__ float As[BK][BM];
    __shared__ float Bs[BK][BN];
    int tid = threadIdx.x;
    int tx = tid & 15, ty = tid >> 4;
    int row0 = blockIdx.y * BM, col0 = blockIdx.x * BN;

    float acc[TM][TN] = {};

    int am = tid >> 2;
    int ak = (tid & 3) * 4;
    int kb = tid >> 4;
    int n4 = (tid & 15) * 4;

    for (int k0 = 0; k0 < K; k0 += BK) {
        float4 av = *(const float4*)&A[(size_t)(row0 + am) * K + k0 + ak];
        As[ak + 0][am] = av.x;
        As[ak + 1][am] = av.y;
        As[ak + 2][am] = av.z;
        As[ak + 3][am] = av.w;
        float4 bv = *(const float4*)&W[(size_t)(k0 + kb) * N + col0 + n4];
        *(float4*)&Bs[kb][n4] = bv;
        __syncthreads();
#pragma unroll
        for (int k = 0; k < BK; ++k) {
            float4 a4 = *(const float4*)&As[k][ty * TM];
            float4 b4 = *(const float4*)&Bs[k][tx * TN];
            float a[TM] = {a4.x, a4.y, a4.z, a4.w};
            float b[TN] = {b4.x, b4.y, b4.z, b4.w};
#pragma unroll
            for (int i = 0; i < TM; ++i)
#pragma unroll
                for (int j = 0; j < TN; ++j) acc[i][j] += a[i] * b[j];
        }
        __syncthreads();
    }

#pragma unroll
    for (int i = 0; i < TM; ++i) {
        int r = row0 + ty * TM + i;
#pragma unroll
        for (int j = 0; j < TN; ++j) {
            int c = col0 + tx * TN + j;
            float v = acc[i][j] + bias[c];
            C[(size_t)r * N + c] = fmaxf(v, 0.0f);
        }
    }
}

// ---------------------------------------------------------------- two-stage pooling
#define PROWS 1024
__global__ __launch_bounds__(256) void k_pool2(const float* __restrict__ X,
                                               const int* __restrict__ bidx,
                                               float* __restrict__ PL) {
    __shared__ float lds[NG * D];   // 16 KB
    int tid = threadIdx.x;
    for (int i = tid; i < NG * D; i += 256) lds[i] = 0.0f;
    __syncthreads();
    int base = blockIdx.x * PROWS;
    int f = tid & 63, rg = tid >> 6;
    for (int r = base + rg; r < base + PROWS; r += 4) {
        int g = bidx[r];
        atomicAdd(&lds[g * D + f], X[(size_t)r * D + f]);
    }
    __syncthreads();
    for (int i = tid; i < NG * D; i += 256) {
        float v = lds[i];
        if (v != 0.0f) fatomic_add(&PL[i], v);
    }
}

// ---------------------------------------------------------------- final linear head
__global__ void k_final(const float* __restrict__ pooled, const float* __restrict__ lin_w,
                        const float* __restrict__ lin_b, float* __restrict__ out) {
    int g = threadIdx.x;
    if (g >= NG) return;
    float acc = lin_b[0];
#pragma unroll
    for (int d2 = 0; d2 < D; ++d2) acc += pooled[g * D + d2] * lin_w[d2];
    out[g] = fmaxf(acc, 0.0f);
}

// ---------------------------------------------------------------- launch
extern "C" void kernel_launch(void* const* d_in, const int* in_sizes, int n_in,
                              void* d_out, int out_size, void* d_ws, size_t ws_size,
                              hipStream_t stream) {
    const float* x0    = (const float*)d_in[0];
    const float* stat  = (const float*)d_in[1];
    const float* W1    = (const float*)d_in[2];
    const float* b1    = (const float*)d_in[3];
    const float* W2    = (const float*)d_in[4];
    const float* b2    = (const float*)d_in[5];
    const float* W3    = (const float*)d_in[6];
    const float* b3    = (const float*)d_in[7];
    const float* eps   = (const float*)d_in[8];
    const float* lin_w = (const float*)d_in[9];
    const float* lin_b = (const float*)d_in[10];
    const int* inner_src = (const int*)d_in[11];
    const int* inner_dst = (const int*)d_in[12];
    const int* fwd_src   = (const int*)d_in[13];
    const int* fwd_dst   = (const int*)d_in[14];
    const int* bwd_src   = (const int*)d_in[15];
    const int* bwd_dst   = (const int*)d_in[16];
    const int* bidx      = (const int*)d_in[17];

    float* X  = (float*)d_ws;                    // NND*D
    float* T  = X  + (size_t)NND * D;            // P*F
    float* H1 = T  + (size_t)P * F;              // P*H
    float* H2 = H1 + (size_t)P * H;              // P*H
    float* PL = H2 + (size_t)P * H;              // NG*D
    int* deg      = (int*)(PL + NG * D);         // NSETS*P
    int* cursor   = deg + (size_t)NSETS * P;     // NSETS*P
    int* rowstart = cursor + (size_t)NSETS * P;  // NSETS*RSP
    int* elist    = rowstart + (size_t)NSETS * RSP; // NSETS*EDG

    // ---- CSR build for all 13 edge sets (3 batched kernels)
    hipMemsetAsync(deg, 0, (size_t)NSETS * P * 2 * sizeof(int), stream);  // deg + cursor
    k_csr_hist<<<(NSETS * EDG) / 256, 256, 0, stream>>>(inner_dst, fwd_dst, bwd_dst, deg);
    k_csr_scan<<<NSETS, 1024, 0, stream>>>(deg, rowstart);
    k_csr_scatter<<<(NSETS * EDG) / 256, 256, 0, stream>>>(inner_src, inner_dst, fwd_src, fwd_dst,
                                                           bwd_src, bwd_dst, rowstart, cursor, elist);

    auto gemm = [&](const float* A, const float* Wm, const float* bs, float* C,
                    int M, int K, int N) {
        dim3 grid(N / BN, M / BM);
        k_gemm<<<grid, 256, 0, stream>>>(A, Wm, bs, C, M, K, N);
    };
    auto mlp = [&](int wi, float* xout) {
        gemm(T,  W1 + (size_t)wi * F * H, b1 + wi * H, H1, P, F, H);
        gemm(H1, W2 + (size_t)wi * H * H, b2 + wi * H, H2, P, H, H);
        gemm(H2, W3 + (size_t)wi * H * D, b3 + wi * D, xout, P, H, D);
    };
    auto conv = [&](int t, int dst_gbase, int src_gbase, int ei) {
        k_gather_T<<<(P * 20) / 256, 256, 0, stream>>>(
            X, stat, elist + (size_t)t * EDG, rowstart + (size_t)t * RSP,
            T, dst_gbase, src_gbase, eps, ei);
    };
    auto build = [&](int gbase) {
        k_build_T<<<(P * F + 255) / 256, 256, 0, stream>>>(X, stat, T, gbase);
    };

    k_init_x<<<(NND * D + 255) / 256, 256, 0, stream>>>(x0, X);

    // forward pass
    for (int il = 0; il < NLAYERS; ++il) {
        int s0 = il * P;
        conv(il, s0, s0, 0);                       // inner conv, mlp 0
        mlp(0, X + (size_t)s0 * D);
        if (il == NLAYERS - 1) continue;
        conv(5 + il, s0 + P, s0, 1);               // fwd conv, mlp 1
        mlp(1, X + (size_t)(s0 + P) * D);
        build(s0 + P);                             // node_dnn, mlp 3
        mlp(3, X + (size_t)(s0 + P) * D);
    }
    // backward pass
    for (int il = NLAYERS - 1; il >= 1; --il) {
        int s0 = (il - 1) * P;
        conv(9 + (il - 1), s0, s0 + P, 2);         // bwd conv, mlp 2
        mlp(2, X + (size_t)s0 * D);
        conv(il - 1, s0, s0, 0);                   // inner conv, mlp 0
        mlp(0, X + (size_t)s0 * D);
        build(s0);                                 // node_dnn, mlp 3
        mlp(3, X + (size_t)s0 * D);
    }

    hipMemsetAsync(PL, 0, NG * D * sizeof(float), stream);
    k_pool2<<<NND / PROWS, 256, 0, stream>>>(X, bidx, PL);
    k_final<<<1, 64, 0, stream>>>(PL, lin_w, lin_b, (float*)d_out);
}

// Round 3
// 1994.237 us; speedup vs baseline: 3.2140x; 1.2911x over previous
//
#include <hip/hip_runtime.h>

#define P 16384
#define NLAYERS 5
#define NND 98304          // P*(NLAYERS+1)
#define D 64
#define S 16
#define F 80               // D+S
#define KP1 96             // K of layer-1 GEMM padded to 32
#define H 256
#define EDG 262144         // 1<<18
#define NG 64
#define NSETS 13           // 5 inner + 4 fwd + 4 bwd
#define RSP 16385          // rowstart pitch (P+1)
#define LDP 40             // LDS K-stride (32 + 8 pad -> 80B rows, 2-way max)

typedef __attribute__((ext_vector_type(8))) short s16x8;
typedef __attribute__((ext_vector_type(4))) float f32x4;

// ---------------------------------------------------------------- utilities
__device__ __forceinline__ void fatomic_add(float* p, float v) {
    unsafeAtomicAdd(p, v);
}
__device__ __forceinline__ unsigned short bf16_rne(float x) {
    unsigned int u = __float_as_uint(x);
    unsigned int r = u + 0x7fffu + ((u >> 16) & 1u);
    return (unsigned short)(r >> 16);
}
__device__ __forceinline__ float bf16_to_f(unsigned short b) {
    return __uint_as_float(((unsigned int)b) << 16);
}

// ---------------------------------------------------------------- init X
__global__ void k_init_x(const float* __restrict__ x0, float* __restrict__ X) {
    int idx = blockIdx.x * blockDim.x + threadIdx.x;
    if (idx >= NND * D) return;
    int row = idx >> 6, f = idx & 63;
    X[idx] = (f == 0) ? x0[row] : 0.0f;
}

// ---------------------------------------------------------------- weight transpose + split
// W [4][K][N] fp32 -> Wh/Wl [4][N][Kp] bf16 (rows kp>=K zero)
__global__ void k_wsplit(const float* __restrict__ W, unsigned short* __restrict__ h,
                         unsigned short* __restrict__ l, int K, int N, int Kp) {
    int idx = blockIdx.x * blockDim.x + threadIdx.x;
    if (idx >= 4 * N * Kp) return;
    int set = idx / (N * Kp), rem = idx - set * (N * Kp);
    int n = rem / Kp, kp = rem - n * Kp;
    float v = (kp < K) ? W[(size_t)set * K * N + (size_t)kp * N + n] : 0.0f;
    unsigned short hh = bf16_rne(v);
    h[idx] = hh;
    l[idx] = bf16_rne(v - bf16_to_f(hh));
}

// ---------------------------------------------------------------- CSR build (batched, 13 sets)
__device__ __forceinline__ const int* set_ptr(int t, const int* inner, const int* fwd,
                                              const int* bwd) {
    if (t < 5) return inner + (size_t)t * EDG;
    if (t < 9) return fwd + (size_t)(t - 5) * EDG;
    return bwd + (size_t)(t - 9) * EDG;
}

__global__ void k_csr_hist(const int* __restrict__ inner_dst, const int* __restrict__ fwd_dst,
                           const int* __restrict__ bwd_dst, int* __restrict__ deg) {
    int idx = blockIdx.x * blockDim.x + threadIdx.x;
    if (idx >= NSETS * EDG) return;
    int t = idx >> 18, e = idx & (EDG - 1);
    const int* dstp = set_ptr(t, inner_dst, fwd_dst, bwd_dst);
    atomicAdd(&deg[t * P + dstp[e]], 1);
}

__global__ __launch_bounds__(1024) void k_csr_scan(const int* __restrict__ deg,
                                                   int* __restrict__ rowstart) {
    __shared__ int part[1024];
    int t = blockIdx.x;
    const int* d = deg + t * P;
    int* rs = rowstart + (size_t)t * RSP;
    int tid = threadIdx.x;
    int base = tid * 16;
    int loc[16], sum = 0;
#pragma unroll
    for (int i = 0; i < 16; ++i) { loc[i] = sum; sum += d[base + i]; }
    part[tid] = sum;
    __syncthreads();
    for (int off = 1; off < 1024; off <<= 1) {
        int v = (tid >= off) ? part[tid - off] : 0;
        __syncthreads();
        part[tid] += v;
        __syncthreads();
    }
    int pre = tid ? part[tid - 1] : 0;
#pragma unroll
    for (int i = 0; i < 16; ++i) rs[base + i] = pre + loc[i];
    if (tid == 1023) rs[P] = pre + sum;
}

__global__ void k_csr_scatter(const int* __restrict__ inner_src, const int* __restrict__ inner_dst,
                              const int* __restrict__ fwd_src, const int* __restrict__ fwd_dst,
                              const int* __restrict__ bwd_src, const int* __restrict__ bwd_dst,
                              const int* __restrict__ rowstart, int* __restrict__ cursor,
                              int* __restrict__ elist) {
    int idx = blockIdx.x * blockDim.x + threadIdx.x;
    if (idx >= NSETS * EDG) return;
    int t = idx >> 18, e = idx & (EDG - 1);
    const int* srcp = set_ptr(t, inner_src, fwd_src, bwd_src);
    const int* dstp = set_ptr(t, inner_dst, fwd_dst, bwd_dst);
    int dv = dstp[e];
    int pos = atomicAdd(&cursor[t * P + dv], 1);
    elist[(size_t)t * EDG + rowstart[(size_t)t * RSP + dv] + pos] = srcp[e];
}

// ---------------------------------------------------------------- gather conv input
// T[v][0:80] = (1+eps[ei]) * concat(X,st)[dst_gbase+v] + sum_{s in adj(v)} concat(X,st)[src_gbase+s]
// T[v][80:96] = 0  (K padded for GEMM1)
__global__ __launch_bounds__(256) void k_gather_T(const float* __restrict__ X,
                                                  const float* __restrict__ st,
                                                  const int* __restrict__ elist,
                                                  const int* __restrict__ rowstart,
                                                  float* __restrict__ T,
                                                  int dst_gbase, int src_gbase,
                                                  const float* __restrict__ eps, int ei) {
    int idx = blockIdx.x * blockDim.x + threadIdx.x;   // P*24 threads exactly
    int v = idx / 24, q = idx - v * 24;
    int f = q * 4;
    if (f >= F) {
        *(float4*)&T[(size_t)v * KP1 + f] = make_float4(0, 0, 0, 0);
        return;
    }
    int beg = rowstart[v], end = rowstart[v + 1];
    float scale = 1.0f + eps[ei];
    int g = dst_gbase + v;
    float4 acc;
    if (f < D) acc = *(const float4*)&X[(size_t)g * D + f];
    else       acc = *(const float4*)&st[(size_t)g * S + (f - D)];
    acc.x *= scale; acc.y *= scale; acc.z *= scale; acc.w *= scale;
    for (int i = beg; i < end; ++i) {
        int s = src_gbase + elist[i];
        float4 val;
        if (f < D) val = *(const float4*)&X[(size_t)s * D + f];
        else       val = *(const float4*)&st[(size_t)s * S + (f - D)];
        acc.x += val.x; acc.y += val.y; acc.z += val.z; acc.w += val.w;
    }
    *(float4*)&T[(size_t)v * KP1 + f] = acc;
}

// ---------------------------------------------------------------- split-bf16 MFMA GEMM
// C[M,N] = relu(A[M,Kp] @ Wt^T + bias), A fp32 (mode0: dense ld=lda; mode1: X||static||0),
// Wt = [N][Kp] bf16 hi/lo. M=16384 fixed. Tile 128x64, 4 waves (2x2), per-wave 64x32.
__global__ __launch_bounds__(256) void k_gemm_mfma(
    const float* __restrict__ A, int lda,
    const float* __restrict__ Xsrc, const float* __restrict__ stsrc, int gbase, int mode,
    const unsigned short* __restrict__ Wh, const unsigned short* __restrict__ Wl, int Kp,
    const float* __restrict__ bias, float* __restrict__ C, int ldc, int N)
{
    __shared__ unsigned short Ah[128][LDP], Al[128][LDP];
    __shared__ unsigned short Bh[64][LDP],  Bl[64][LDP];

    int tid = threadIdx.x;
    int lane = tid & 63, wid = tid >> 6;
    int wm = wid >> 1, wn = wid & 1;
    int m0 = blockIdx.y * 128, n0 = blockIdx.x * 64;

    f32x4 acc[4][2] = {};

    int ar = tid >> 1, akb = (tid & 1) * 16;   // A staging: 128 rows x 2 half-rows
    int br = tid >> 2, bq = (tid & 3) * 8;     // B staging: 64 rows x 4 chunks

    int arow_g = m0 + ar;
    int la = lane & 15, lg = lane >> 4;

    for (int k0 = 0; k0 < Kp; k0 += 32) {
        // ---- stage A: fp32 -> split bf16 hi/lo
#pragma unroll
        for (int j = 0; j < 4; ++j) {
            int kk = akb + j * 4;
            int k = k0 + kk;
            float4 v;
            if (mode == 0) {
                v = *(const float4*)&A[(size_t)arow_g * lda + k];
            } else {
                int g = gbase + arow_g;
                if (k < D)      v = *(const float4*)&Xsrc[(size_t)g * D + k];
                else if (k < F) v = *(const float4*)&stsrc[(size_t)g * S + (k - D)];
                else            v = make_float4(0, 0, 0, 0);
            }
            ushort4 hh, ll;
            hh.x = bf16_rne(v.x); ll.x = bf16_rne(v.x - bf16_to_f(hh.x));
            hh.y = bf16_rne(v.y); ll.y = bf16_rne(v.y - bf16_to_f(hh.y));
            hh.z = bf16_rne(v.z); ll.z = bf16_rne(v.z - bf16_to_f(hh.z));
            hh.w = bf16_rne(v.w); ll.w = bf16_rne(v.w - bf16_to_f(hh.w));
            *(ushort4*)&Ah[ar][kk] = hh;
            *(ushort4*)&Al[ar][kk] = ll;
        }
        // ---- stage B: copy pre-split bf16 weights
        {
            size_t off = (size_t)(n0 + br) * Kp + k0 + bq;
            *(s16x8*)&Bh[br][bq] = *(const s16x8*)&Wh[off];
            *(s16x8*)&Bl[br][bq] = *(const s16x8*)&Wl[off];
        }
        __syncthreads();

        // ---- fragments + MFMA
        int kf = lg * 8;
        s16x8 ah[4], al[4], bh[2], bl[2];
#pragma unroll
        for (int m = 0; m < 4; ++m) {
            int r = wm * 64 + m * 16 + la;
            ah[m] = *(const s16x8*)&Ah[r][kf];
            al[m] = *(const s16x8*)&Al[r][kf];
        }
#pragma unroll
        for (int n = 0; n < 2; ++n) {
            int r = wn * 32 + n * 16 + la;
            bh[n] = *(const s16x8*)&Bh[r][kf];
            bl[n] = *(const s16x8*)&Bl[r][kf];
        }
#pragma unroll
        for (int m = 0; m < 4; ++m)
#pragma unroll
            for (int n = 0; n < 2; ++n) {
                acc[m][n] = __builtin_amdgcn_mfma_f32_16x16x32_bf16(ah[m], bh[n], acc[m][n], 0, 0, 0);
                acc[m][n] = __builtin_amdgcn_mfma_f32_16x16x32_bf16(ah[m], bl[n], acc[m][n], 0, 0, 0);
                acc[m][n] = __builtin_amdgcn_mfma_f32_16x16x32_bf16(al[m], bh[n], acc[m][n], 0, 0, 0);
            }
        __syncthreads();
    }

    // ---- epilogue: bias + relu
#pragma unroll
    for (int n = 0; n < 2; ++n) {
        int col = n0 + wn * 32 + n * 16 + la;
        float bv = bias[col];
#pragma unroll
        for (int m = 0; m < 4; ++m) {
            int row = m0 + wm * 64 + m * 16 + lg * 4;
#pragma unroll
            for (int r = 0; r < 4; ++r) {
                C[(size_t)(row + r) * ldc + col] = fmaxf(acc[m][n][r] + bv, 0.0f);
            }
        }
    }
}

// ---------------------------------------------------------------- two-stage pooling
#define PROWS 1024
__global__ __launch_bounds__(256) void k_pool2(const float* __restrict__ X,
                                               const int* __restrict__ bidx,
                                               float* __restrict__ PL) {
    __shared__ float lds[NG * D];
    int tid = threadIdx.x;
    for (int i = tid; i < NG * D; i += 256) lds[i] = 0.0f;
    __syncthreads();
    int base = blockIdx.x * PROWS;
    int f = tid & 63, rg = tid >> 6;
    for (int r = base + rg; r < base + PROWS; r += 4) {
        int g = bidx[r];
        atomicAdd(&lds[g * D + f], X[(size_t)r * D + f]);
    }
    __syncthreads();
    for (int i = tid; i < NG * D; i += 256) {
        float v = lds[i];
        if (v != 0.0f) fatomic_add(&PL[i], v);
    }
}

// ---------------------------------------------------------------- final linear head
__global__ void k_final(const float* __restrict__ pooled, const float* __restrict__ lin_w,
                        const float* __restrict__ lin_b, float* __restrict__ out) {
    int g = threadIdx.x;
    if (g >= NG) return;
    float acc = lin_b[0];
#pragma unroll
    for (int d2 = 0; d2 < D; ++d2) acc += pooled[g * D + d2] * lin_w[d2];
    out[g] = fmaxf(acc, 0.0f);
}

// ---------------------------------------------------------------- launch
extern "C" void kernel_launch(void* const* d_in, const int* in_sizes, int n_in,
                              void* d_out, int out_size, void* d_ws, size_t ws_size,
                              hipStream_t stream) {
    const float* x0    = (const float*)d_in[0];
    const float* stat  = (const float*)d_in[1];
    const float* W1    = (const float*)d_in[2];
    const float* b1    = (const float*)d_in[3];
    const float* W2    = (const float*)d_in[4];
    const float* b2    = (const float*)d_in[5];
    const float* W3    = (const float*)d_in[6];
    const float* b3    = (const float*)d_in[7];
    const float* eps   = (const float*)d_in[8];
    const float* lin_w = (const float*)d_in[9];
    const float* lin_b = (const float*)d_in[10];
    const int* inner_src = (const int*)d_in[11];
    const int* inner_dst = (const int*)d_in[12];
    const int* fwd_src   = (const int*)d_in[13];
    const int* fwd_dst   = (const int*)d_in[14];
    const int* bwd_src   = (const int*)d_in[15];
    const int* bwd_dst   = (const int*)d_in[16];
    const int* bidx      = (const int*)d_in[17];

    float* X  = (float*)d_ws;                        // NND*64
    float* T  = X  + (size_t)NND * D;                // P*96
    float* H1 = T  + (size_t)P * KP1;                // P*256
    float* H2 = H1 + (size_t)P * H;                  // P*256
    float* PL = H2 + (size_t)P * H;                  // NG*64
    int* deg      = (int*)(PL + NG * D);             // NSETS*P
    int* cursor   = deg + (size_t)NSETS * P;         // NSETS*P
    int* rowstart = cursor + (size_t)NSETS * P;      // NSETS*RSP
    int* elist    = rowstart + (size_t)NSETS * RSP;  // NSETS*EDG
    unsigned short* w1h = (unsigned short*)(elist + (size_t)NSETS * EDG);
    unsigned short* w1l = w1h + (size_t)4 * H * KP1;     // [4][256][96]
    unsigned short* w2h = w1l + (size_t)4 * H * KP1;     // [4][256][256]
    unsigned short* w2l = w2h + (size_t)4 * H * H;
    unsigned short* w3h = w2l + (size_t)4 * H * H;       // [4][64][256]
    unsigned short* w3l = w3h + (size_t)4 * D * H;

    // ---- weight prep (once per launch)
    k_wsplit<<<(4 * H * KP1 + 255) / 256, 256, 0, stream>>>(W1, w1h, w1l, F, H, KP1);
    k_wsplit<<<(4 * H * H + 255) / 256, 256, 0, stream>>>(W2, w2h, w2l, H, H, H);
    k_wsplit<<<(4 * D * H + 255) / 256, 256, 0, stream>>>(W3, w3h, w3l, H, D, H);

    // ---- CSR build for all 13 edge sets
    hipMemsetAsync(deg, 0, (size_t)NSETS * P * 2 * sizeof(int), stream);
    k_csr_hist<<<(NSETS * EDG) / 256, 256, 0, stream>>>(inner_dst, fwd_dst, bwd_dst, deg);
    k_csr_scan<<<NSETS, 1024, 0, stream>>>(deg, rowstart);
    k_csr_scatter<<<(NSETS * EDG) / 256, 256, 0, stream>>>(inner_src, inner_dst, fwd_src, fwd_dst,
                                                           bwd_src, bwd_dst, rowstart, cursor, elist);

    auto gemm1T = [&](int set) {   // A = T (mode 0, ld 96)
        k_gemm_mfma<<<dim3(H / 64, P / 128), 256, 0, stream>>>(
            T, KP1, nullptr, nullptr, 0, 0,
            w1h + (size_t)set * H * KP1, w1l + (size_t)set * H * KP1, KP1,
            b1 + set * H, H1, H, H);
    };
    auto gemm1X = [&](int set, int gbase) {   // A = X||static (mode 1)
        k_gemm_mfma<<<dim3(H / 64, P / 128), 256, 0, stream>>>(
            nullptr, 0, X, stat, gbase, 1,
            w1h + (size_t)set * H * KP1, w1l + (size_t)set * H * KP1, KP1,
            b1 + set * H, H1, H, H);
    };
    auto gemm23 = [&](int set, int gbase_out) {
        k_gemm_mfma<<<dim3(H / 64, P / 128), 256, 0, stream>>>(
            H1, H, nullptr, nullptr, 0, 0,
            w2h + (size_t)set * H * H, w2l + (size_t)set * H * H, H,
            b2 + set * H, H2, H, H);
        k_gemm_mfma<<<dim3(D / 64, P / 128), 256, 0, stream>>>(
            H2, H, nullptr, nullptr, 0, 0,
            w3h + (size_t)set * D * H, w3l + (size_t)set * D * H, H,
            b3 + set * D, X + (size_t)gbase_out * D, D, D);
    };
    auto conv = [&](int t, int dst_gbase, int src_gbase, int ei, int set) {
        k_gather_T<<<(P * 24) / 256, 256, 0, stream>>>(
            X, stat, elist + (size_t)t * EDG, rowstart + (size_t)t * RSP,
            T, dst_gbase, src_gbase, eps, ei);
        gemm1T(set);
        gemm23(set, dst_gbase);
    };
    auto node_dnn = [&](int gbase) {
        gemm1X(3, gbase);
        gemm23(3, gbase);
    };

    k_init_x<<<(NND * D + 255) / 256, 256, 0, stream>>>(x0, X);

    // forward pass
    for (int il = 0; il < NLAYERS; ++il) {
        int s0 = il * P;
        conv(il, s0, s0, 0, 0);                       // inner conv
        if (il == NLAYERS - 1) continue;
        conv(5 + il, s0 + P, s0, 1, 1);               // fwd conv
        node_dnn(s0 + P);
    }
    // backward pass
    for (int il = NLAYERS - 1; il >= 1; --il) {
        int s0 = (il - 1) * P;
        conv(9 + (il - 1), s0, s0 + P, 2, 2);         // bwd conv
        conv(il - 1, s0, s0, 0, 0);                   // inner conv
        node_dnn(s0);
    }

    hipMemsetAsync(PL, 0, NG * D * sizeof(float), stream);
    k_pool2<<<NND / PROWS, 256, 0, stream>>>(X, bidx, PL);
    k_final<<<1, 64, 0, stream>>>(PL, lin_w, lin_b, (float*)d_out);
}

// Round 5
// 1833.737 us; speedup vs baseline: 3.4953x; 1.0875x over previous
//
#include <hip/hip_runtime.h>

#define P 16384
#define NLAYERS 5
#define NND 98304          // P*(NLAYERS+1)
#define D 64
#define S 16
#define F 80               // D+S
#define KP1 96             // K of layer-1 GEMM padded to 32
#define H 256
#define EDG 262144         // 1<<18
#define NG 64
#define NSETS 13           // 5 inner + 4 fwd + 4 bwd
#define RSP 16385          // rowstart pitch (P+1)
#define LDP 40             // LDS K-stride (32 + 8 pad -> 80B rows, <=2-way aliasing)

typedef __attribute__((ext_vector_type(8))) short s16x8;
typedef __attribute__((ext_vector_type(4))) float f32x4;

// ---------------------------------------------------------------- utilities
__device__ __forceinline__ void fatomic_add(float* p, float v) {
    unsafeAtomicAdd(p, v);
}
__device__ __forceinline__ unsigned short bf16_rne(float x) {
    unsigned int u = __float_as_uint(x);
    unsigned int r = u + 0x7fffu + ((u >> 16) & 1u);
    return (unsigned short)(r >> 16);
}
__device__ __forceinline__ float bf16_to_f(unsigned short b) {
    return __uint_as_float(((unsigned int)b) << 16);
}

// ---------------------------------------------------------------- init X
__global__ void k_init_x(const float* __restrict__ x0, float* __restrict__ X) {
    int idx = blockIdx.x * blockDim.x + threadIdx.x;
    if (idx >= NND * D) return;
    int row = idx >> 6, f = idx & 63;
    X[idx] = (f == 0) ? x0[row] : 0.0f;
}

// ---------------------------------------------------------------- weight transpose + split
// W [4][K][N] fp32 -> Wh/Wl [4][N][Kp] bf16 (rows kp>=K zero)
__global__ void k_wsplit(const float* __restrict__ W, unsigned short* __restrict__ h,
                         unsigned short* __restrict__ l, int K, int N, int Kp) {
    int idx = blockIdx.x * blockDim.x + threadIdx.x;
    if (idx >= 4 * N * Kp) return;
    int set = idx / (N * Kp), rem = idx - set * (N * Kp);
    int n = rem / Kp, kp = rem - n * Kp;
    float v = (kp < K) ? W[(size_t)set * K * N + (size_t)kp * N + n] : 0.0f;
    unsigned short hh = bf16_rne(v);
    h[idx] = hh;
    l[idx] = bf16_rne(v - bf16_to_f(hh));
}

// ---------------------------------------------------------------- CSR build (batched, 13 sets)
__device__ __forceinline__ const int* set_ptr(int t, const int* inner, const int* fwd,
                                              const int* bwd) {
    if (t < 5) return inner + (size_t)t * EDG;
    if (t < 9) return fwd + (size_t)(t - 5) * EDG;
    return bwd + (size_t)(t - 9) * EDG;
}

// histogram + per-edge rank (atomicAdd return value), rank written coalesced
__global__ void k_csr_hist(const int* __restrict__ inner_dst, const int* __restrict__ fwd_dst,
                           const int* __restrict__ bwd_dst, int* __restrict__ deg,
                           int* __restrict__ rank) {
    int idx = blockIdx.x * blockDim.x + threadIdx.x;
    if (idx >= NSETS * EDG) return;
    int t = idx >> 18, e = idx & (EDG - 1);
    const int* dstp = set_ptr(t, inner_dst, fwd_dst, bwd_dst);
    rank[idx] = atomicAdd(&deg[t * P + dstp[e]], 1);
}

__global__ __launch_bounds__(1024) void k_csr_scan(const int* __restrict__ deg,
                                                   int* __restrict__ rowstart) {
    __shared__ int part[1024];
    int t = blockIdx.x;
    const int* d = deg + t * P;
    int* rs = rowstart + (size_t)t * RSP;
    int tid = threadIdx.x;
    int base = tid * 16;
    int loc[16], sum = 0;
#pragma unroll
    for (int i = 0; i < 16; ++i) { loc[i] = sum; sum += d[base + i]; }
    part[tid] = sum;
    __syncthreads();
    for (int off = 1; off < 1024; off <<= 1) {
        int v = (tid >= off) ? part[tid - off] : 0;
        __syncthreads();
        part[tid] += v;
        __syncthreads();
    }
    int pre = tid ? part[tid - 1] : 0;
#pragma unroll
    for (int i = 0; i < 16; ++i) rs[base + i] = pre + loc[i];
    if (tid == 1023) rs[P] = pre + sum;
}

// pure-store scatter using precomputed ranks (no cursor atomics)
__global__ void k_csr_scatter(const int* __restrict__ inner_src, const int* __restrict__ inner_dst,
                              const int* __restrict__ fwd_src, const int* __restrict__ fwd_dst,
                              const int* __restrict__ bwd_src, const int* __restrict__ bwd_dst,
                              const int* __restrict__ rowstart, const int* __restrict__ rank,
                              int* __restrict__ elist) {
    int idx = blockIdx.x * blockDim.x + threadIdx.x;
    if (idx >= NSETS * EDG) return;
    int t = idx >> 18, e = idx & (EDG - 1);
    const int* srcp = set_ptr(t, inner_src, fwd_src, bwd_src);
    const int* dstp = set_ptr(t, inner_dst, fwd_dst, bwd_dst);
    int dv = dstp[e];
    elist[(size_t)t * EDG + rowstart[(size_t)t * RSP + dv] + rank[idx]] = srcp[e];
}

// ---------------------------------------------------------------- gather conv input (writes split planes)
// T[v][0:80] = (1+eps[ei]) * concat(X,st)[dst_gbase+v] + sum_{s in adj(v)} concat(X,st)[src_gbase+s]
// T[v][80:96] = 0  (K padded for GEMM1)
__global__ __launch_bounds__(256) void k_gather_T(const float* __restrict__ X,
                                                  const float* __restrict__ st,
                                                  const int* __restrict__ elist,
                                                  const int* __restrict__ rowstart,
                                                  unsigned short* __restrict__ Th,
                                                  unsigned short* __restrict__ Tl,
                                                  int dst_gbase, int src_gbase,
                                                  const float* __restrict__ eps, int ei) {
    int idx = blockIdx.x * blockDim.x + threadIdx.x;   // P*24 threads exactly
    int v = idx / 24, q = idx - v * 24;
    int f = q * 4;
    if (f >= F) {
        *(ushort4*)&Th[(size_t)v * KP1 + f] = make_ushort4(0, 0, 0, 0);
        *(ushort4*)&Tl[(size_t)v * KP1 + f] = make_ushort4(0, 0, 0, 0);
        return;
    }
    int beg = rowstart[v], end = rowstart[v + 1];
    float scale = 1.0f + eps[ei];
    int g = dst_gbase + v;
    float4 acc;
    if (f < D) acc = *(const float4*)&X[(size_t)g * D + f];
    else       acc = *(const float4*)&st[(size_t)g * S + (f - D)];
    acc.x *= scale; acc.y *= scale; acc.z *= scale; acc.w *= scale;
    for (int i = beg; i < end; ++i) {
        int s = src_gbase + elist[i];
        float4 val;
        if (f < D) val = *(const float4*)&X[(size_t)s * D + f];
        else       val = *(const float4*)&st[(size_t)s * S + (f - D)];
        acc.x += val.x; acc.y += val.y; acc.z += val.z; acc.w += val.w;
    }
    ushort4 hh, ll;
    hh.x = bf16_rne(acc.x); ll.x = bf16_rne(acc.x - bf16_to_f(hh.x));
    hh.y = bf16_rne(acc.y); ll.y = bf16_rne(acc.y - bf16_to_f(hh.y));
    hh.z = bf16_rne(acc.z); ll.z = bf16_rne(acc.z - bf16_to_f(hh.z));
    hh.w = bf16_rne(acc.w); ll.w = bf16_rne(acc.w - bf16_to_f(hh.w));
    *(ushort4*)&Th[(size_t)v * KP1 + f] = hh;
    *(ushort4*)&Tl[(size_t)v * KP1 + f] = ll;
}

// ---------------------------------------------------------------- split-bf16 MFMA GEMM, copy staging
// C = relu(A @ Wt^T + bias); A given as split planes (CV=false) or as fp32 X||static||0 (CV=true).
// Wt = [N][Kp] split planes. Tile 128x64, 4 waves (2x2), per-wave 64x32, BK=32.
template<bool CV>
__global__ __launch_bounds__(256) void k_gemm_sp(
    const unsigned short* __restrict__ Ahp, const unsigned short* __restrict__ Alp, int lda,
    const float* __restrict__ Xsrc, const float* __restrict__ stsrc, int gbase,
    const unsigned short* __restrict__ Wh, const unsigned short* __restrict__ Wl, int Kp,
    const float* __restrict__ bias,
    float* __restrict__ Cf, unsigned short* __restrict__ Ch, unsigned short* __restrict__ Cl,
    int ldc)
{
    __shared__ unsigned short Ah[128][LDP], Al[128][LDP];
    __shared__ unsigned short Bh[64][LDP],  Bl[64][LDP];

    int tid = threadIdx.x;
    int lane = tid & 63, wid = tid >> 6;
    int wm = wid >> 1, wn = wid & 1;
    int m0 = blockIdx.y * 128, n0 = blockIdx.x * 64;

    f32x4 acc[4][2] = {};

    int sr = tid >> 2;              // staging row (0..63), A also uses sr+64
    int sc = (tid & 3) * 8;         // staging chunk (8 elems = 16B)
    int la = lane & 15, lg = lane >> 4;

    for (int k0 = 0; k0 < Kp; k0 += 32) {
        if (!CV) {
            // A: two rows per thread, pure copy
            size_t o0 = (size_t)(m0 + sr) * lda + k0 + sc;
            size_t o1 = (size_t)(m0 + sr + 64) * lda + k0 + sc;
            *(s16x8*)&Ah[sr][sc]      = *(const s16x8*)&Ahp[o0];
            *(s16x8*)&Al[sr][sc]      = *(const s16x8*)&Alp[o0];
            *(s16x8*)&Ah[sr + 64][sc] = *(const s16x8*)&Ahp[o1];
            *(s16x8*)&Al[sr + 64][sc] = *(const s16x8*)&Alp[o1];
        } else {
            // A: convert from fp32 X||static||0 (node_dnn path)
#pragma unroll
            for (int hrow = 0; hrow < 2; ++hrow) {
                int r = sr + hrow * 64;
                int g = gbase + m0 + r;
                int k = k0 + sc;
                float vv[8];
                if (k < D) {
                    float4 a = *(const float4*)&Xsrc[(size_t)g * D + k];
                    float4 b = *(const float4*)&Xsrc[(size_t)g * D + k + 4];
                    vv[0]=a.x; vv[1]=a.y; vv[2]=a.z; vv[3]=a.w;
                    vv[4]=b.x; vv[5]=b.y; vv[6]=b.z; vv[7]=b.w;
                } else if (k < F) {
                    float4 a = *(const float4*)&stsrc[(size_t)g * S + (k - D)];
                    float4 b = *(const float4*)&stsrc[(size_t)g * S + (k - D) + 4];
                    vv[0]=a.x; vv[1]=a.y; vv[2]=a.z; vv[3]=a.w;
                    vv[4]=b.x; vv[5]=b.y; vv[6]=b.z; vv[7]=b.w;
                } else {
#pragma unroll
                    for (int j = 0; j < 8; ++j) vv[j] = 0.0f;
                }
                ushort4 h0, h1, l0, l1;
                h0.x=bf16_rne(vv[0]); l0.x=bf16_rne(vv[0]-bf16_to_f(h0.x));
                h0.y=bf16_rne(vv[1]); l0.y=bf16_rne(vv[1]-bf16_to_f(h0.y));
                h0.z=bf16_rne(vv[2]); l0.z=bf16_rne(vv[2]-bf16_to_f(h0.z));
                h0.w=bf16_rne(vv[3]); l0.w=bf16_rne(vv[3]-bf16_to_f(h0.w));
                h1.x=bf16_rne(vv[4]); l1.x=bf16_rne(vv[4]-bf16_to_f(h1.x));
                h1.y=bf16_rne(vv[5]); l1.y=bf16_rne(vv[5]-bf16_to_f(h1.y));
                h1.z=bf16_rne(vv[6]); l1.z=bf16_rne(vv[6]-bf16_to_f(h1.z));
                h1.w=bf16_rne(vv[7]); l1.w=bf16_rne(vv[7]-bf16_to_f(h1.w));
                *(ushort4*)&Ah[r][sc]     = h0;
                *(ushort4*)&Ah[r][sc + 4] = h1;
                *(ushort4*)&Al[r][sc]     = l0;
                *(ushort4*)&Al[r][sc + 4] = l1;
            }
        }
        // B: one row per thread, pure copy
        {
            size_t ob = (size_t)(n0 + sr) * Kp + k0 + sc;
            *(s16x8*)&Bh[sr][sc] = *(const s16x8*)&Wh[ob];
            *(s16x8*)&Bl[sr][sc] = *(const s16x8*)&Wl[ob];
        }
        __syncthreads();

        int kf = lg * 8;
        s16x8 ah[4], al[4], bh[2], bl[2];
#pragma unroll
        for (int m = 0; m < 4; ++m) {
            int r = wm * 64 + m * 16 + la;
            ah[m] = *(const s16x8*)&Ah[r][kf];
            al[m] = *(const s16x8*)&Al[r][kf];
        }
#pragma unroll
        for (int n = 0; n < 2; ++n) {
            int r = wn * 32 + n * 16 + la;
            bh[n] = *(const s16x8*)&Bh[r][kf];
            bl[n] = *(const s16x8*)&Bl[r][kf];
        }
#pragma unroll
        for (int m = 0; m < 4; ++m)
#pragma unroll
            for (int n = 0; n < 2; ++n) {
                acc[m][n] = __builtin_amdgcn_mfma_f32_16x16x32_bf16(ah[m], bh[n], acc[m][n], 0, 0, 0);
                acc[m][n] = __builtin_amdgcn_mfma_f32_16x16x32_bf16(ah[m], bl[n], acc[m][n], 0, 0, 0);
                acc[m][n] = __builtin_amdgcn_mfma_f32_16x16x32_bf16(al[m], bh[n], acc[m][n], 0, 0, 0);
            }
        __syncthreads();
    }

    // epilogue: bias + relu; write fp32 or split planes
#pragma unroll
    for (int n = 0; n < 2; ++n) {
        int col = n0 + wn * 32 + n * 16 + la;
        float bv = bias[col];
#pragma unroll
        for (int m = 0; m < 4; ++m) {
            int row = m0 + wm * 64 + m * 16 + lg * 4;
#pragma unroll
            for (int r = 0; r < 4; ++r) {
                float v = fmaxf(acc[m][n][r] + bv, 0.0f);
                size_t o = (size_t)(row + r) * ldc + col;
                if (Cf) {
                    Cf[o] = v;
                } else {
                    unsigned short hh = bf16_rne(v);
                    Ch[o] = hh;
                    Cl[o] = bf16_rne(v - bf16_to_f(hh));
                }
            }
        }
    }
}

// ---------------------------------------------------------------- two-stage pooling
#define PROWS 1024
__global__ __launch_bounds__(256) void k_pool2(const float* __restrict__ X,
                                               const int* __restrict__ bidx,
                                               float* __restrict__ PL) {
    __shared__ float lds[NG * D];
    int tid = threadIdx.x;
    for (int i = tid; i < NG * D; i += 256) lds[i] = 0.0f;
    __syncthreads();
    int base = blockIdx.x * PROWS;
    int f = tid & 63, rg = tid >> 6;
    for (int r = base + rg; r < base + PROWS; r += 4) {
        int g = bidx[r];
        atomicAdd(&lds[g * D + f], X[(size_t)r * D + f]);
    }
    __syncthreads();
    for (int i = tid; i < NG * D; i += 256) {
        float v = lds[i];
        if (v != 0.0f) fatomic_add(&PL[i], v);
    }
}

// ---------------------------------------------------------------- final linear head
__global__ void k_final(const float* __restrict__ pooled, const float* __restrict__ lin_w,
                        const float* __restrict__ lin_b, float* __restrict__ out) {
    int g = threadIdx.x;
    if (g >= NG) return;
    float acc = lin_b[0];
#pragma unroll
    for (int d2 = 0; d2 < D; ++d2) acc += pooled[g * D + d2] * lin_w[d2];
    out[g] = fmaxf(acc, 0.0f);
}

// ---------------------------------------------------------------- launch
extern "C" void kernel_launch(void* const* d_in, const int* in_sizes, int n_in,
                              void* d_out, int out_size, void* d_ws, size_t ws_size,
                              hipStream_t stream) {
    const float* x0    = (const float*)d_in[0];
    const float* stat  = (const float*)d_in[1];
    const float* W1    = (const float*)d_in[2];
    const float* b1    = (const float*)d_in[3];
    const float* W2    = (const float*)d_in[4];
    const float* b2    = (const float*)d_in[5];
    const float* W3    = (const float*)d_in[6];
    const float* b3    = (const float*)d_in[7];
    const float* eps   = (const float*)d_in[8];
    const float* lin_w = (const float*)d_in[9];
    const float* lin_b = (const float*)d_in[10];
    const int* inner_src = (const int*)d_in[11];
    const int* inner_dst = (const int*)d_in[12];
    const int* fwd_src   = (const int*)d_in[13];
    const int* fwd_dst   = (const int*)d_in[14];
    const int* bwd_src   = (const int*)d_in[15];
    const int* bwd_dst   = (const int*)d_in[16];
    const int* bidx      = (const int*)d_in[17];

    float* X  = (float*)d_ws;                                 // NND*64 f32
    float* PL = X + (size_t)NND * D;                          // NG*64 f32
    unsigned short* Th  = (unsigned short*)(PL + NG * D);     // [P][96]
    unsigned short* Tl  = Th  + (size_t)P * KP1;
    unsigned short* H1h = Tl  + (size_t)P * KP1;              // [P][256]
    unsigned short* H1l = H1h + (size_t)P * H;
    unsigned short* H2h = H1l + (size_t)P * H;                // [P][256]
    unsigned short* H2l = H2h + (size_t)P * H;
    unsigned short* w1h = H2l + (size_t)P * H;                // [4][256][96]
    unsigned short* w1l = w1h + (size_t)4 * H * KP1;
    unsigned short* w2h = w1l + (size_t)4 * H * KP1;          // [4][256][256]
    unsigned short* w2l = w2h + (size_t)4 * H * H;
    unsigned short* w3h = w2l + (size_t)4 * H * H;            // [4][64][256]
    unsigned short* w3l = w3h + (size_t)4 * D * H;
    int* deg      = (int*)(w3l + (size_t)4 * D * H);          // NSETS*P
    int* rowstart = deg + (size_t)NSETS * P;                  // NSETS*RSP
    int* rank     = rowstart + (size_t)NSETS * RSP;           // NSETS*EDG
    int* elist    = rank + (size_t)NSETS * EDG;               // NSETS*EDG

    // ---- weight prep (once per launch)
    k_wsplit<<<(4 * H * KP1 + 255) / 256, 256, 0, stream>>>(W1, w1h, w1l, F, H, KP1);
    k_wsplit<<<(4 * H * H + 255) / 256, 256, 0, stream>>>(W2, w2h, w2l, H, H, H);
    k_wsplit<<<(4 * D * H + 255) / 256, 256, 0, stream>>>(W3, w3h, w3l, H, D, H);

    // ---- CSR build for all 13 edge sets
    hipMemsetAsync(deg, 0, (size_t)NSETS * P * sizeof(int), stream);
    k_csr_hist<<<(NSETS * EDG) / 256, 256, 0, stream>>>(inner_dst, fwd_dst, bwd_dst, deg, rank);
    k_csr_scan<<<NSETS, 1024, 0, stream>>>(deg, rowstart);
    k_csr_scatter<<<(NSETS * EDG) / 256, 256, 0, stream>>>(inner_src, inner_dst, fwd_src, fwd_dst,
                                                           bwd_src, bwd_dst, rowstart, rank, elist);

    auto gemm1T = [&](int set) {
        k_gemm_sp<false><<<dim3(H / 64, P / 128), 256, 0, stream>>>(
            Th, Tl, KP1, nullptr, nullptr, 0,
            w1h + (size_t)set * H * KP1, w1l + (size_t)set * H * KP1, KP1,
            b1 + set * H, nullptr, H1h, H1l, H);
    };
    auto gemm1X = [&](int set, int gbase) {
        k_gemm_sp<true><<<dim3(H / 64, P / 128), 256, 0, stream>>>(
            nullptr, nullptr, 0, X, stat, gbase,
            w1h + (size_t)set * H * KP1, w1l + (size_t)set * H * KP1, KP1,
            b1 + set * H, nullptr, H1h, H1l, H);
    };
    auto gemm23 = [&](int set, int gbase_out) {
        k_gemm_sp<false><<<dim3(H / 64, P / 128), 256, 0, stream>>>(
            H1h, H1l, H, nullptr, nullptr, 0,
            w2h + (size_t)set * H * H, w2l + (size_t)set * H * H, H,
            b2 + set * H, nullptr, H2h, H2l, H);
        k_gemm_sp<false><<<dim3(D / 64, P / 128), 256, 0, stream>>>(
            H2h, H2l, H, nullptr, nullptr, 0,
            w3h + (size_t)set * D * H, w3l + (size_t)set * D * H, H,
            b3 + set * D, X + (size_t)gbase_out * D, nullptr, nullptr, D);
    };
    auto conv = [&](int t, int dst_gbase, int src_gbase, int ei, int set) {
        k_gather_T<<<(P * 24) / 256, 256, 0, stream>>>(
            X, stat, elist + (size_t)t * EDG, rowstart + (size_t)t * RSP,
            Th, Tl, dst_gbase, src_gbase, eps, ei);
        gemm1T(set);
        gemm23(set, dst_gbase);
    };
    auto node_dnn = [&](int gbase) {
        gemm1X(3, gbase);
        gemm23(3, gbase);
    };

    k_init_x<<<(NND * D + 255) / 256, 256, 0, stream>>>(x0, X);

    // forward pass
    for (int il = 0; il < NLAYERS; ++il) {
        int s0 = il * P;
        conv(il, s0, s0, 0, 0);                       // inner conv
        if (il == NLAYERS - 1) continue;
        conv(5 + il, s0 + P, s0, 1, 1);               // fwd conv
        node_dnn(s0 + P);
    }
    // backward pass
    for (int il = NLAYERS - 1; il >= 1; --il) {
        int s0 = (il - 1) * P;
        conv(9 + (il - 1), s0, s0 + P, 2, 2);         // bwd conv
        conv(il - 1, s0, s0, 0, 0);                   // inner conv
        node_dnn(s0);
    }

    hipMemsetAsync(PL, 0, NG * D * sizeof(float), stream);
    k_pool2<<<NND / PROWS, 256, 0, stream>>>(X, bidx, PL);
    k_final<<<1, 64, 0, stream>>>(PL, lin_w, lin_b, (float*)d_out);
}